// Round 2
// 869.499 us; speedup vs baseline: 2.2043x; 2.2043x over previous
//
#include <hip/hip_runtime.h>
#include <math.h>

constexpr int kE = 32;    // experts
constexpr int kH = 2048;  // hidden
constexpr int kI = 768;   // expert intermediate dim
constexpr int kT = 2048;  // tokens
constexpr int kK = 4;     // top-k

typedef _Float16 half8  __attribute__((ext_vector_type(8)));
typedef _Float16 half4v __attribute__((ext_vector_type(4)));
typedef float    float4v __attribute__((ext_vector_type(4)));

// Workspace layout (bytes):
//   [0,256)    expert_offsets int[kE+1]
//   [256,..)   token_ids int[8192]
//   then       token_w  float[8192]
//   [65792,..) gated    _Float16[8192][768]  (~12.6 MB)
constexpr size_t kOffsOff  = 0;
constexpr size_t kTokOff   = 256;
constexpr size_t kTwOff    = 256 + (size_t)kT * kK * 4;
constexpr size_t kGatedOff = 65792;

// ---------------------------------------------------------------------------
// Routing (unchanged — verified correct). numpy scatter semantics:
// last duplicate wins, expert contributes once.
// ---------------------------------------------------------------------------
__global__ __launch_bounds__(256) void route_kernel(
    const int* __restrict__ ridx, const float* __restrict__ rw,
    int* __restrict__ offs, int* __restrict__ tok, float* __restrict__ tw) {
  __shared__ int s_cnt[kE];
  __shared__ int s_off[kE + 1];
  __shared__ int s_cur[kE];
  const int tid = threadIdx.x;
  if (tid < kE) { s_cnt[tid] = 0; s_cur[tid] = 0; }
  __syncthreads();
  for (int i = tid; i < kT * kK; i += 256) {
    const int t = i >> 2, k = i & 3;
    const int e = ridx[i];
    bool last = true;
    for (int k2 = k + 1; k2 < kK; ++k2)
      if (ridx[t * kK + k2] == e) last = false;
    if (last) atomicAdd(&s_cnt[e], 1);
  }
  __syncthreads();
  if (tid == 0) {
    int acc = 0;
    for (int e = 0; e < kE; ++e) { s_off[e] = acc; acc += s_cnt[e]; }
    s_off[kE] = acc;
  }
  __syncthreads();
  if (tid <= kE) offs[tid] = s_off[tid];
  for (int i = tid; i < kT * kK; i += 256) {
    const int t = i >> 2, k = i & 3;
    const int e = ridx[i];
    bool last = true;
    for (int k2 = k + 1; k2 < kK; ++k2)
      if (ridx[t * kK + k2] == e) last = false;
    if (last) {
      const int p = atomicAdd(&s_cur[e], 1);
      const int g = s_off[e] + p;
      tok[g] = t;
      tw[g] = rw[i];
    }
  }
}

// ---------------------------------------------------------------------------
// Gate-up MFMA kernel. Block: 256 thr = 4 waves. Tile: 128 tokens x
// (64 gate cols + 64 up cols). Wave (wm,wn): 64 rows x (32 gate + 32 up).
// MFMA 16x16x32 f16, fp32 acc.
//
// R2 changes:
//  * blockIdx.x decode is e = x&31, tt = x>>5 so ACTIVE blocks (tt small)
//    occupy contiguous IDs 0..~63 -> spread across all 8 XCDs instead of
//    landing on id%16 in {0,1} (= 2 XCDs). Also puts both token-tiles of an
//    expert on the same XCD -> weight slab L2 reuse.
//  * global->register double-buffer: K-loop unrolled x2 with named register
//    sets; next sub-tile's loads issue while current sub-tile computes.
// ---------------------------------------------------------------------------
__global__ __launch_bounds__(256) void gateup_kernel(
    const float* __restrict__ hs, const float* __restrict__ gup,
    const int* __restrict__ offs, const int* __restrict__ tok,
    _Float16* __restrict__ gated) {
  const int e  = blockIdx.x & 31;   // dense active IDs: e fast, tt slow
  const int tt = blockIdx.x >> 5;
  const int base = offs[e];
  const int Ne = offs[e + 1] - base;
  if (tt * 128 >= Ne) return;
  const int i0 = blockIdx.y * 64;
  const int total = offs[kE];

  __shared__ _Float16 Asb[128 * 40];  // [row][k] k-contiguous, stride 40
  __shared__ _Float16 Bsb[128 * 40];  // [n][k] transposed; n<64 gate, n>=64 up

  const int tid = threadIdx.x;
  // A staging: thread covers rows ar+32i (i<4), k-chunk ak0..ak0+3
  const int ar  = tid >> 3;
  const int ak0 = (tid & 7) * 4;
  size_t arow[4];
#pragma unroll
  for (int i = 0; i < 4; ++i) {
    int slot = base + tt * 128 + ar + 32 * i;
    slot = slot < total ? slot : total - 1;
    arow[i] = (size_t)tok[slot] * kH;
  }
  // B staging: thread owns col n=bn, k-chunks bk+16p (p<2), 4 k each
  const int bn = tid & 63;
  const int bk = (tid >> 6) * 4;
  const float* gupe = gup + (size_t)e * kH * (2 * kI);

  const int lane = tid & 63, wave = tid >> 6;
  const int m16 = lane & 15, quad = lane >> 4;
  const int wm = wave >> 1, wn = wave & 1;

  float4v accg[4][2], accu[4][2];
#pragma unroll
  for (int mt = 0; mt < 4; ++mt)
#pragma unroll
    for (int nt = 0; nt < 2; ++nt) {
      accg[mt][nt] = (float4v){0.f, 0.f, 0.f, 0.f};
      accu[mt][nt] = (float4v){0.f, 0.f, 0.f, 0.f};
    }

  // ---- double-buffered register staging ----
  float4 avA[4], avB[4];
  float bgA[2][4], buA[2][4], bgB[2][4], buB[2][4];

  auto gload = [&](int kk, float4 (&av)[4], float (&bg)[2][4],
                   float (&bu)[2][4]) {
#pragma unroll
    for (int i = 0; i < 4; ++i)
      av[i] = *(const float4*)(hs + arow[i] + kk + ak0);
#pragma unroll
    for (int p = 0; p < 2; ++p) {
      const int k0 = bk + 16 * p;
      const float* bp = gupe + (size_t)(kk + k0) * (2 * kI) + i0 + bn;
#pragma unroll
      for (int j = 0; j < 4; ++j) {
        bg[p][j] = bp[(size_t)j * (2 * kI)];
        bu[p][j] = bp[(size_t)j * (2 * kI) + kI];
      }
    }
  };

  auto lstore = [&](const float4 (&av)[4], const float (&bg)[2][4],
                    const float (&bu)[2][4]) {
#pragma unroll
    for (int i = 0; i < 4; ++i)
      *(half4v*)&Asb[(ar + 32 * i) * 40 + ak0] =
          (half4v){(_Float16)av[i].x, (_Float16)av[i].y,
                   (_Float16)av[i].z, (_Float16)av[i].w};
#pragma unroll
    for (int p = 0; p < 2; ++p) {
      const int k0 = bk + 16 * p;
      *(half4v*)&Bsb[bn * 40 + k0] =
          (half4v){(_Float16)bg[p][0], (_Float16)bg[p][1],
                   (_Float16)bg[p][2], (_Float16)bg[p][3]};
      *(half4v*)&Bsb[(bn + 64) * 40 + k0] =
          (half4v){(_Float16)bu[p][0], (_Float16)bu[p][1],
                   (_Float16)bu[p][2], (_Float16)bu[p][3]};
    }
  };

  auto compute = [&]() {
    half8 af[4];
#pragma unroll
    for (int mt = 0; mt < 4; ++mt)
      af[mt] = *(const half8*)&Asb[(wm * 64 + mt * 16 + m16) * 40 + quad * 8];
    half8 bfg[2], bfu[2];
#pragma unroll
    for (int nt = 0; nt < 2; ++nt) {
      bfg[nt] = *(const half8*)&Bsb[(wn * 32 + nt * 16 + m16) * 40 + quad * 8];
      bfu[nt] =
          *(const half8*)&Bsb[(64 + wn * 32 + nt * 16 + m16) * 40 + quad * 8];
    }
#pragma unroll
    for (int mt = 0; mt < 4; ++mt)
#pragma unroll
      for (int nt = 0; nt < 2; ++nt) {
        accg[mt][nt] = __builtin_amdgcn_mfma_f32_16x16x32_f16(
            af[mt], bfg[nt], accg[mt][nt], 0, 0, 0);
        accu[mt][nt] = __builtin_amdgcn_mfma_f32_16x16x32_f16(
            af[mt], bfu[nt], accu[mt][nt], 0, 0, 0);
      }
  };

  gload(0, avA, bgA, buA);
  for (int kk = 0; kk < kH; kk += 64) {
    __syncthreads();               // prev frag reads done; LDS reusable
    lstore(avA, bgA, buA);
    gload(kk + 32, avB, bgB, buB); // in flight across compute phase
    __syncthreads();
    compute();
    __syncthreads();
    lstore(avB, bgB, buB);
    if (kk + 64 < kH) gload(kk + 64, avA, bgA, buA);
    __syncthreads();
    compute();
  }

  // epilogue: SwiGLU, store fp16 gated. D layout: row=quad*4+r, col=m16.
#pragma unroll
  for (int mt = 0; mt < 4; ++mt)
#pragma unroll
    for (int r = 0; r < 4; ++r) {
      const int rr = tt * 128 + wm * 64 + mt * 16 + quad * 4 + r;
      if (rr < Ne) {
        _Float16* gp = gated + (size_t)(base + rr) * kI + i0 + wn * 32 + m16;
#pragma unroll
        for (int nt = 0; nt < 2; ++nt) {
          const float g = accg[mt][nt][r];
          const float u = accu[mt][nt][r];
          gp[nt * 16] = (_Float16)(u * g / (1.f + expf(-g)));
        }
      }
    }
}

// ---------------------------------------------------------------------------
// Down-proj MFMA kernel. Block tile: 128 slots x 128 H-cols. Wave: 64x64.
// Same R2 changes: dense active block IDs + register double-buffer.
// ---------------------------------------------------------------------------
__global__ __launch_bounds__(256) void down_kernel(
    const _Float16* __restrict__ gated, const float* __restrict__ dn,
    const int* __restrict__ offs, const int* __restrict__ tok,
    const float* __restrict__ tw, float* __restrict__ out) {
  const int e  = blockIdx.x & 31;   // dense active IDs
  const int tt = blockIdx.x >> 5;
  const int base = offs[e];
  const int Ne = offs[e + 1] - base;
  if (tt * 128 >= Ne) return;
  const int h0 = blockIdx.y * 128;
  const int total = offs[kE];

  __shared__ _Float16 Asb[128 * 40];
  __shared__ _Float16 Bsb[128 * 40];

  const int tid = threadIdx.x;
  // A staging: units u = tid + 256i (i<2): row = u>>2, k8 = (u&3)*8
  const int ar  = tid >> 2;         // 0..63 (+64i)
  const int ak8 = (tid & 3) * 8;
  size_t arow[2];
#pragma unroll
  for (int i = 0; i < 2; ++i) {
    int slot = base + tt * 128 + ar + 64 * i;
    slot = slot < total ? slot : total - 1;
    arow[i] = (size_t)slot * kI;
  }
  // B staging: col n = tid&127; k-chunks bk+8g (g<4), 4 k each
  const int bn = tid & 127;
  const int bk = (tid >> 7) * 4;    // 0 or 4
  const float* dne = dn + (size_t)e * kI * kH;

  const int lane = tid & 63, wave = tid >> 6;
  const int m16 = lane & 15, quad = lane >> 4;
  const int wm = wave >> 1, wn = wave & 1;

  float4v acc[4][4];
#pragma unroll
  for (int mt = 0; mt < 4; ++mt)
#pragma unroll
    for (int nt = 0; nt < 4; ++nt) acc[mt][nt] = (float4v){0.f, 0.f, 0.f, 0.f};

  // ---- double-buffered register staging ----
  half8 a8A[2], a8B[2];
  float bwA[4][4], bwB[4][4];

  auto gload = [&](int kk, half8 (&a8)[2], float (&bw)[4][4]) {
#pragma unroll
    for (int i = 0; i < 2; ++i)
      a8[i] = *(const half8*)(gated + arow[i] + kk + ak8);
#pragma unroll
    for (int g = 0; g < 4; ++g) {
      const int k0 = bk + 8 * g;
#pragma unroll
      for (int j = 0; j < 4; ++j)
        bw[g][j] = dne[(size_t)(kk + k0 + j) * kH + h0 + bn];
    }
  };

  auto lstore = [&](const half8 (&a8)[2], const float (&bw)[4][4]) {
#pragma unroll
    for (int i = 0; i < 2; ++i)
      *(half8*)&Asb[(ar + 64 * i) * 40 + ak8] = a8[i];
#pragma unroll
    for (int g = 0; g < 4; ++g) {
      const int k0 = bk + 8 * g;
      *(half4v*)&Bsb[bn * 40 + k0] =
          (half4v){(_Float16)bw[g][0], (_Float16)bw[g][1],
                   (_Float16)bw[g][2], (_Float16)bw[g][3]};
    }
  };

  auto compute = [&]() {
    half8 af[4], bf[4];
#pragma unroll
    for (int mt = 0; mt < 4; ++mt)
      af[mt] = *(const half8*)&Asb[(wm * 64 + mt * 16 + m16) * 40 + quad * 8];
#pragma unroll
    for (int nt = 0; nt < 4; ++nt)
      bf[nt] = *(const half8*)&Bsb[(wn * 64 + nt * 16 + m16) * 40 + quad * 8];
#pragma unroll
    for (int mt = 0; mt < 4; ++mt)
#pragma unroll
      for (int nt = 0; nt < 4; ++nt)
        acc[mt][nt] = __builtin_amdgcn_mfma_f32_16x16x32_f16(
            af[mt], bf[nt], acc[mt][nt], 0, 0, 0);
  };

  gload(0, a8A, bwA);
  for (int kk = 0; kk < kI; kk += 64) {
    __syncthreads();
    lstore(a8A, bwA);
    gload(kk + 32, a8B, bwB);
    __syncthreads();
    compute();
    __syncthreads();
    lstore(a8B, bwB);
    if (kk + 64 < kI) gload(kk + 64, a8A, bwA);
    __syncthreads();
    compute();
  }

  // epilogue
#pragma unroll
  for (int mt = 0; mt < 4; ++mt)
#pragma unroll
    for (int r = 0; r < 4; ++r) {
      const int rr = tt * 128 + wm * 64 + mt * 16 + quad * 4 + r;
      if (rr < Ne) {
        const int s = base + rr;
        const int t = tok[s];
        const float w = tw[s];
        float* op = out + (size_t)t * kH + h0 + wn * 64 + m16;
#pragma unroll
        for (int nt = 0; nt < 4; ++nt)
          atomicAdd(&op[nt * 16], acc[mt][nt][r] * w);
      }
    }
}

extern "C" void kernel_launch(void* const* d_in, const int* in_sizes, int n_in,
                              void* d_out, int out_size, void* d_ws, size_t ws_size,
                              hipStream_t stream) {
  const float* hs   = (const float*)d_in[0];
  const float* rw   = (const float*)d_in[1];
  const int*   ridx = (const int*)d_in[2];
  const float* gup  = (const float*)d_in[4];
  const float* dn   = (const float*)d_in[5];
  float* out = (float*)d_out;

  char* ws = (char*)d_ws;
  int*      offs  = (int*)(ws + kOffsOff);
  int*      tok   = (int*)(ws + kTokOff);
  float*    tw    = (float*)(ws + kTwOff);
  _Float16* gated = (_Float16*)(ws + kGatedOff);

  hipMemsetAsync(d_out, 0, (size_t)kT * kH * sizeof(float), stream);
  route_kernel<<<1, 256, 0, stream>>>(ridx, rw, offs, tok, tw);
  gateup_kernel<<<dim3(32 * 16, kI / 64), 256, 0, stream>>>(hs, gup, offs, tok, gated);
  down_kernel<<<dim3(32 * 16, kH / 128), 256, 0, stream>>>(gated, dn, offs, tok, tw, out);
}